// Round 17
// baseline (127.752 us; speedup 1.0000x reference)
//
#include <hip/hip_runtime.h>

#define NN 100000
#define EE 1000000
#define IN_F 128
#define HID_F 64
#define OUT_F 40
#define BUCKET 48      // fixed CSR stride, multiple of 8; max degree ~28-34 ≪ 48
#define BIN_NODES 256
#define NBINS 391      // ceil(NN/256)
#define FIFO_CAP 4096  // per-bin FIFO capacity (mean 2558)
#define P1_CHUNK 2048
#define P1_BUF 16
#define NWORK 1563     // ceil(NN/64)

typedef _Float16 half8 __attribute__((ext_vector_type(8)));
typedef _Float16 half4 __attribute__((ext_vector_type(4)));
typedef float f32x4 __attribute__((ext_vector_type(4)));

#define SWZ(b, row) ((b) ^ (((row) & 7) << 4))

static __device__ __forceinline__ int atomic_add_i32(int* p, int v) {
    return __hip_atomic_fetch_add(p, v, __ATOMIC_RELAXED, __HIP_MEMORY_SCOPE_AGENT);
}

static __device__ __forceinline__ f32x4 h4f4(half4 h) {
    f32x4 r = {(float)h.x, (float)h.y, (float)h.z, (float)h.w};
    return r;
}

// Fused: bincur zero + W1 transpose->fp16 + W2 transpose->fp16(48-pad)
__global__ __launch_bounds__(256) void k_prep(const float* __restrict__ W1,
                                              const float* __restrict__ W2,
                                              _Float16* __restrict__ w1t,
                                              _Float16* __restrict__ w2t,
                                              int* __restrict__ bincur) {
    int i = blockIdx.x * 256 + threadIdx.x;
    if (i < IN_F * HID_F) {
        int k = i >> 6, n = i & 63;
        w1t[n * IN_F + k] = (_Float16)W1[i];
    }
    if (i < 48 * HID_F) {
        int n = i >> 6, k = i & 63;
        w2t[i] = (_Float16)((n < OUT_F) ? W2[k * OUT_F + n] : 0.f);
    }
    if (i < NBINS) bincur[i] = 0;
}

// Phase 1: LDS-binned edge scatter into per-bin FIFOs. (round-12 proven)
__global__ __launch_bounds__(256) void k_bin(const int* __restrict__ ei,
                                             int* __restrict__ bincur,
                                             unsigned* __restrict__ fifo) {
    __shared__ unsigned buf[NBINS][P1_BUF];   // 25 KB
    __shared__ int lcnt[NBINS];
    __shared__ int lbase[NBINS];
    const int tid = threadIdx.x;
    for (int j = tid; j < NBINS; j += 256) lcnt[j] = 0;
    __syncthreads();

    const int e0 = blockIdx.x * P1_CHUNK;
    #pragma unroll
    for (int i = 0; i < P1_CHUNK / 256; ++i) {
        int e = e0 + i * 256 + tid;
        if (e < EE) {
            int s = ei[e];
            int d = ei[EE + e];
            int bin = d >> 8;
            unsigned pk = ((unsigned)s << 8) | (unsigned)(d & 255);
            int p = atomicAdd(&lcnt[bin], 1);          // LDS atomic
            if (p < P1_BUF) {
                buf[bin][p] = pk;
            } else {                                   // rare overflow: direct append
                int gp = atomic_add_i32(&bincur[bin], 1);
                if (gp < FIFO_CAP) fifo[(size_t)bin * FIFO_CAP + gp] = pk;
            }
        }
    }
    __syncthreads();
    for (int j = tid; j < NBINS; j += 256) {
        int cnt = lcnt[j]; if (cnt > P1_BUF) cnt = P1_BUF;
        lbase[j] = (cnt > 0) ? atomic_add_i32(&bincur[j], cnt) : 0;
        lcnt[j] = cnt;
    }
    __syncthreads();
    for (int j = tid; j < NBINS; j += 256) {
        int cnt = lcnt[j];
        int base = lbase[j];
        for (int k = 0; k < cnt; ++k) {
            int gp = base + k;
            if (gp < FIFO_CAP) fifo[(size_t)j * FIFO_CAP + gp] = buf[j][k];
        }
    }
}

// Phase 2: one WG per bin. Replay FIFO with LDS atomics into LDS CSR tile,
// pad to multiple of 8 with zero-row index NN, flush int4. (round-12 proven)
__global__ __launch_bounds__(256) void k_csr(const int* __restrict__ bincur,
                                             const unsigned* __restrict__ fifo,
                                             int* __restrict__ csr,
                                             int* __restrict__ deg,
                                             float* __restrict__ dinv) {
    __shared__ int cur[BIN_NODES];                 // 1 KB
    __shared__ int stage[BIN_NODES * BUCKET];      // 48 KB
    const int tid = threadIdx.x;
    const int bin = blockIdx.x;
    const int v0 = bin * BIN_NODES;
    const int nnode = (NN - v0 < BIN_NODES) ? (NN - v0) : BIN_NODES;
    if (tid < BIN_NODES) cur[tid] = 0;
    __syncthreads();

    int cnt = bincur[bin]; if (cnt > FIFO_CAP) cnt = FIFO_CAP;
    for (int k = tid; k < cnt; k += 256) {
        unsigned u = fifo[(size_t)bin * FIFO_CAP + k];
        int dl = u & 255;
        int s = (int)(u >> 8);
        int p = atomicAdd(&cur[dl], 1);            // LDS atomic
        if (p < BUCKET) stage[dl * BUCKET + p] = s;
    }
    __syncthreads();

    if (tid < nnode) {                             // pad to multiple of 8 with NN
        int d = cur[tid]; if (d > BUCKET) d = BUCKET;
        int dpad = (d + 7) & ~7; if (dpad > BUCKET) dpad = BUCKET;
        for (int k = d; k < dpad; ++k) stage[tid * BUCKET + k] = NN;
        cur[tid] = d;
    }
    __syncthreads();

    const int total4 = nnode * BUCKET / 4;
    int4* dst4 = (int4*)&csr[(size_t)v0 * BUCKET];
    for (int idx = tid; idx < total4; idx += 256)
        dst4[idx] = *(const int4*)&stage[idx * 4];
    if (tid < nnode) {
        int d = cur[tid];
        deg[v0 + tid] = d;
        dinv[v0 + tid] = rsqrtf((float)(d + 1));
    }
}

// h1sl[s][row][16] = fp16( dinv * (x @ W1) ) column-sliced; row NN = zeros.
__global__ __launch_bounds__(256) void k_gemm1(const float* __restrict__ x,
                                               const _Float16* __restrict__ w1t,
                                               const float* __restrict__ dinv,
                                               _Float16* __restrict__ h1sl) {
    __shared__ _Float16 As[64 * IN_F];
    __shared__ _Float16 Bs[64 * IN_F];
    const int tid = threadIdx.x;
    const size_t r0 = (size_t)blockIdx.x * 64;

    #pragma unroll
    for (int i = 0; i < 8; ++i) {
        int f = i * 256 + tid;
        int row = f >> 5;
        int k4 = (f & 31) * 4;
        size_t gr = r0 + row; if (gr >= NN) gr = NN - 1;
        float4 v = *(const float4*)&x[gr * IN_F + k4];
        _Float16 h[4] = {(_Float16)v.x, (_Float16)v.y, (_Float16)v.z, (_Float16)v.w};
        *(uint2*)((char*)As + SWZ(row * 256 + k4 * 2, row)) = *(uint2*)h;
    }
    #pragma unroll
    for (int i = 0; i < 4; ++i) {
        int c = i * 256 + tid;
        int col = c >> 4;
        int k8 = (c & 15) * 8;
        uint4 v = *(const uint4*)&w1t[col * IN_F + k8];
        *(uint4*)((char*)Bs + SWZ(col * 256 + k8 * 2, col)) = v;
    }
    __syncthreads();

    const int w = tid >> 6, l = tid & 63;
    const int lr = l & 15, lg = l >> 4;
    const int R0 = w * 16;
    f32x4 acc[4] = {};
    #pragma unroll
    for (int kk = 0; kk < 4; ++kk) {
        const int kbyte = (kk * 32 + lg * 8) * 2;
        const int arow = R0 + lr;
        half8 a = *(const half8*)((const char*)As + SWZ(arow * 256 + kbyte, arow));
        #pragma unroll
        for (int t = 0; t < 4; ++t) {
            const int bcol = t * 16 + lr;
            half8 b = *(const half8*)((const char*)Bs + SWZ(bcol * 256 + kbyte, bcol));
            acc[t] = __builtin_amdgcn_mfma_f32_16x16x32_f16(a, b, acc[t], 0, 0, 0);
        }
    }
    #pragma unroll
    for (int r = 0; r < 4; ++r) {
        size_t row = r0 + R0 + lg * 4 + r;
        if (row < NN) {
            float dv = dinv[row];
            #pragma unroll
            for (int t = 0; t < 4; ++t)
                h1sl[((size_t)t * (NN + 1) + row) * 16 + lr] = (_Float16)(dv * acc[t][r]);
        } else if (row == NN) {
            #pragma unroll
            for (int t = 0; t < 4; ++t)
                h1sl[((size_t)t * (NN + 1) + row) * 16 + lr] = (_Float16)0.f;
        }
    }
}

// agg1, XCD-sliced: slice s = (blockIdx%8)>>1 runs on XCDs {2s,2s+1}; its 3.2 MB
// table slice stays L2-resident. 4-lane group per node, 64 nodes/block, 8-wide
// padded gather, fp32 accum. hrelusl[s][v][16] = relu(dinv*sum + b1-slice).
__global__ __launch_bounds__(256) void k_agg1sl(const _Float16* __restrict__ h1sl,
                                                const float* __restrict__ dinv,
                                                const int* __restrict__ deg,
                                                const int* __restrict__ csr,
                                                const float* __restrict__ b1,
                                                _Float16* __restrict__ hrelusl) {
    const int b = blockIdx.x;
    const int s = (b & 7) >> 1;
    const int w = ((b >> 3) << 1) | (b & 1);
    if (w >= NWORK) return;
    const int tid = threadIdx.x;
    const int v = w * 64 + (tid >> 2);
    if (v >= NN) return;
    const int c = tid & 3;

    const _Float16* tab = h1sl + (size_t)s * (NN + 1) * 16;
    int dg = deg[v];
    if (dg > BUCKET) dg = BUCKET;
    const int iters = (dg + 7) >> 3;
    const int4* cp = (const int4*)&csr[(size_t)v * BUCKET];

    f32x4 accA = h4f4(*(const half4*)&tab[(size_t)v * 16 + c * 4]);   // self
    f32x4 accB = {};
    for (int it = 0; it < iters; ++it) {
        int4 sa = cp[2 * it];
        int4 sb = cp[2 * it + 1];
        half4 a0 = *(const half4*)&tab[(size_t)sa.x * 16 + c * 4];
        half4 a1 = *(const half4*)&tab[(size_t)sa.y * 16 + c * 4];
        half4 a2 = *(const half4*)&tab[(size_t)sa.z * 16 + c * 4];
        half4 a3 = *(const half4*)&tab[(size_t)sa.w * 16 + c * 4];
        half4 a4 = *(const half4*)&tab[(size_t)sb.x * 16 + c * 4];
        half4 a5 = *(const half4*)&tab[(size_t)sb.y * 16 + c * 4];
        half4 a6 = *(const half4*)&tab[(size_t)sb.z * 16 + c * 4];
        half4 a7 = *(const half4*)&tab[(size_t)sb.w * 16 + c * 4];
        accA += h4f4(a0); accB += h4f4(a1); accA += h4f4(a2); accB += h4f4(a3);
        accA += h4f4(a4); accB += h4f4(a5); accA += h4f4(a6); accB += h4f4(a7);
    }
    accA += accB;

    const float dv = dinv[v];
    float4 bb = *(const float4*)&b1[s * 16 + c * 4];
    _Float16 o[4];
    o[0] = (_Float16)fmaxf(dv * accA[0] + bb.x, 0.f);
    o[1] = (_Float16)fmaxf(dv * accA[1] + bb.y, 0.f);
    o[2] = (_Float16)fmaxf(dv * accA[2] + bb.z, 0.f);
    o[3] = (_Float16)fmaxf(dv * accA[3] + bb.w, 0.f);
    *(uint2*)&hrelusl[((size_t)s * (NN + 1) + v) * 16 + c * 4] = *(uint2*)o;
}

// gemm2: h2 = dinv * (hrelu @ W2) from sliced hrelu; writes sliced tab
// tabsl[t][row][16] (t=0..2, cols t*16.. ; cols >= 40 zeroed). Row NN = zeros.
__global__ __launch_bounds__(256) void k_gemm2(const _Float16* __restrict__ hrelusl,
                                               const _Float16* __restrict__ w2t,
                                               const float* __restrict__ dinv,
                                               _Float16* __restrict__ tabsl) {
    __shared__ _Float16 As[64 * HID_F];  // 8 KB, swizzled rows of 128B
    __shared__ _Float16 Bs[48 * HID_F];  // 6 KB
    const int tid = threadIdx.x;
    const size_t r0 = (size_t)blockIdx.x * 64;

    #pragma unroll
    for (int i = 0; i < 2; ++i) {          // 512 uint4 chunks: row, slice-half
        int cI = i * 256 + tid;
        int row = cI >> 3;
        int sc = cI & 7;                   // slice = sc>>1, half = sc&1
        size_t gr = r0 + row; if (gr >= NN) gr = NN - 1;
        const _Float16* src = hrelusl + ((size_t)(sc >> 1) * (NN + 1) + gr) * 16 + (sc & 1) * 8;
        uint4 v = *(const uint4*)src;
        *(uint4*)((char*)As + SWZ(row * 128 + sc * 16, row)) = v;
    }
    for (int cB = tid; cB < 384; cB += 256) {
        int col = cB >> 3;
        int k8 = (cB & 7) * 8;
        uint4 vB = *(const uint4*)&w2t[col * HID_F + k8];
        *(uint4*)((char*)Bs + SWZ(col * 128 + k8 * 2, col)) = vB;
    }
    __syncthreads();

    const int w = tid >> 6, l = tid & 63;
    const int lr = l & 15, lg = l >> 4;
    const int R0 = w * 16;
    f32x4 acc[3] = {};
    #pragma unroll
    for (int kk = 0; kk < 2; ++kk) {
        const int kbyte = (kk * 32 + lg * 8) * 2;
        const int arow = R0 + lr;
        half8 a = *(const half8*)((const char*)As + SWZ(arow * 128 + kbyte, arow));
        #pragma unroll
        for (int t = 0; t < 3; ++t) {
            const int bcol = t * 16 + lr;
            half8 b = *(const half8*)((const char*)Bs + SWZ(bcol * 128 + kbyte, bcol));
            acc[t] = __builtin_amdgcn_mfma_f32_16x16x32_f16(a, b, acc[t], 0, 0, 0);
        }
    }
    #pragma unroll
    for (int r = 0; r < 4; ++r) {
        size_t row = r0 + R0 + lg * 4 + r;
        if (row < NN) {
            float dv = dinv[row];
            #pragma unroll
            for (int t = 0; t < 3; ++t) {
                int col = t * 16 + lr;
                float val = (col < OUT_F) ? dv * acc[t][r] : 0.f;
                tabsl[((size_t)t * (NN + 1) + row) * 16 + lr] = (_Float16)val;
            }
        } else if (row == NN) {
            #pragma unroll
            for (int t = 0; t < 3; ++t)
                tabsl[((size_t)t * (NN + 1) + row) * 16 + lr] = (_Float16)0.f;
        }
    }
}

// agg2, XCD-sliced: 3 slices (cols 0-15 / 16-31 / 32-39+pad) on XCD sets
// {0,1,2} / {3,4,5} / {6,7}. 4-lane group per node; slice-2 lanes c>=2 idle.
__global__ __launch_bounds__(256) void k_agg2sl(const _Float16* __restrict__ tabsl,
                                                const float* __restrict__ dinv,
                                                const int* __restrict__ deg,
                                                const int* __restrict__ csr,
                                                const float* __restrict__ b2,
                                                float* __restrict__ out) {
    const int b = blockIdx.x;
    const int m = b & 7;
    int s, i3, per;
    if (m < 3)      { s = 0; i3 = m;     per = 3; }
    else if (m < 6) { s = 1; i3 = m - 3; per = 3; }
    else            { s = 2; i3 = m - 6; per = 2; }
    const int w = (b >> 3) * per + i3;
    if (w >= NWORK) return;
    const int tid = threadIdx.x;
    const int c = tid & 3;
    if (s == 2 && c >= 2) return;          // cols 40-47 don't exist
    const int v = w * 64 + (tid >> 2);
    if (v >= NN) return;

    const _Float16* tab = tabsl + (size_t)s * (NN + 1) * 16;
    int dg = deg[v];
    if (dg > BUCKET) dg = BUCKET;
    const int iters = (dg + 7) >> 3;
    const int4* cp = (const int4*)&csr[(size_t)v * BUCKET];

    f32x4 accA = h4f4(*(const half4*)&tab[(size_t)v * 16 + c * 4]);   // self
    f32x4 accB = {};
    for (int it = 0; it < iters; ++it) {
        int4 sa = cp[2 * it];
        int4 sb = cp[2 * it + 1];
        half4 a0 = *(const half4*)&tab[(size_t)sa.x * 16 + c * 4];
        half4 a1 = *(const half4*)&tab[(size_t)sa.y * 16 + c * 4];
        half4 a2 = *(const half4*)&tab[(size_t)sa.z * 16 + c * 4];
        half4 a3 = *(const half4*)&tab[(size_t)sa.w * 16 + c * 4];
        half4 a4 = *(const half4*)&tab[(size_t)sb.x * 16 + c * 4];
        half4 a5 = *(const half4*)&tab[(size_t)sb.y * 16 + c * 4];
        half4 a6 = *(const half4*)&tab[(size_t)sb.z * 16 + c * 4];
        half4 a7 = *(const half4*)&tab[(size_t)sb.w * 16 + c * 4];
        accA += h4f4(a0); accB += h4f4(a1); accA += h4f4(a2); accB += h4f4(a3);
        accA += h4f4(a4); accB += h4f4(a5); accA += h4f4(a6); accB += h4f4(a7);
    }
    accA += accB;

    const int col0 = s * 16 + c * 4;
    if (col0 < OUT_F) {
        const float dv = dinv[v];
        float4 bb = *(const float4*)&b2[col0];
        float4 o = {dv * accA[0] + bb.x, dv * accA[1] + bb.y,
                    dv * accA[2] + bb.z, dv * accA[3] + bb.w};
        *(float4*)&out[(size_t)v * OUT_F + col0] = o;
    }
}

extern "C" void kernel_launch(void* const* d_in, const int* in_sizes, int n_in,
                              void* d_out, int out_size, void* d_ws, size_t ws_size,
                              hipStream_t stream) {
    const float* x  = (const float*)d_in[0];
    const int*   ei = (const int*)d_in[1];
    const float* W1 = (const float*)d_in[2];
    const float* b1 = (const float*)d_in[3];
    const float* W2 = (const float*)d_in[4];
    const float* b2 = (const float*)d_in[5];
    float* out = (float*)d_out;

    char* p = (char*)d_ws;
    float*     dinv    = (float*)p;     p += (size_t)NN * 4;
    int*       deg     = (int*)p;       p += (size_t)NN * 4;
    int*       bincur  = (int*)p;       p += 512 * 4;
    unsigned*  fifo    = (unsigned*)p;  p += (size_t)NBINS * FIFO_CAP * 4;
    _Float16*  w1t     = (_Float16*)p;  p += (size_t)IN_F * HID_F * 2;
    _Float16*  w2t     = (_Float16*)p;  p += (size_t)48 * HID_F * 2;
    int*       csr     = (int*)p;       p += (size_t)NN * BUCKET * 4;
    _Float16*  h1sl    = (_Float16*)p;  p += (size_t)4 * (NN + 1) * 16 * 2;  // 4 slices
    _Float16*  hrelusl = (_Float16*)p;  p += (size_t)4 * (NN + 1) * 16 * 2;  // 4 slices
    _Float16*  tabsl   = (_Float16*)p;  p += (size_t)3 * (NN + 1) * 16 * 2;  // 3 slices

    const int gemm_blocks = NWORK;              // 1563, covers row NN
    const int bin_blocks = (EE + P1_CHUNK - 1) / P1_CHUNK;
    const int sl_blocks = ((NWORK + 1) / 2) * 8;  // 6256: slice-grid (2 blocks/8 min)

    k_prep  <<<32, 256, 0, stream>>>(W1, W2, w1t, w2t, bincur);
    k_bin   <<<bin_blocks, 256, 0, stream>>>(ei, bincur, fifo);
    k_csr   <<<NBINS, 256, 0, stream>>>(bincur, fifo, csr, deg, dinv);
    k_gemm1 <<<gemm_blocks, 256, 0, stream>>>(x, w1t, dinv, h1sl);
    k_agg1sl<<<sl_blocks, 256, 0, stream>>>(h1sl, dinv, deg, csr, b1, hrelusl);
    k_gemm2 <<<gemm_blocks, 256, 0, stream>>>(hrelusl, w2t, dinv, tabsl);
    k_agg2sl<<<sl_blocks, 256, 0, stream>>>(tabsl, dinv, deg, csr, b2, out);
}

// Round 18
// 106.134 us; speedup vs baseline: 1.2037x; 1.2037x over previous
//
#include <hip/hip_runtime.h>

#define NN 100000
#define EE 1000000
#define IN_F 128
#define HID_F 64
#define OUT_F 40
#define BUCKET 48      // fixed CSR stride, multiple of 8; max degree ~28-34 ≪ 48
#define BIN_NODES 256
#define NBINS 391      // ceil(NN/256)
#define FIFO_CAP 4096  // per-bin FIFO capacity (mean 2558)
#define P1_CHUNK 2048
#define P1_BUF 16

typedef _Float16 half8 __attribute__((ext_vector_type(8)));
typedef _Float16 half4 __attribute__((ext_vector_type(4)));
typedef float f32x4 __attribute__((ext_vector_type(4)));

#define SWZ(b, row) ((b) ^ (((row) & 7) << 4))

static __device__ __forceinline__ int atomic_add_i32(int* p, int v) {
    return __hip_atomic_fetch_add(p, v, __ATOMIC_RELAXED, __HIP_MEMORY_SCOPE_AGENT);
}

static __device__ __forceinline__ f32x4 h4f4(half4 h) {
    f32x4 r = {(float)h.x, (float)h.y, (float)h.z, (float)h.w};
    return r;
}

// Fused: bincur zero + W1 transpose->fp16 + W2 transpose->fp16(48-pad)
__global__ __launch_bounds__(256) void k_prep(const float* __restrict__ W1,
                                              const float* __restrict__ W2,
                                              _Float16* __restrict__ w1t,
                                              _Float16* __restrict__ w2t,
                                              int* __restrict__ bincur) {
    int i = blockIdx.x * 256 + threadIdx.x;
    if (i < IN_F * HID_F) {
        int k = i >> 6, n = i & 63;
        w1t[n * IN_F + k] = (_Float16)W1[i];
    }
    if (i < 48 * HID_F) {
        int n = i >> 6, k = i & 63;
        w2t[i] = (_Float16)((n < OUT_F) ? W2[k * OUT_F + n] : 0.f);
    }
    if (i < NBINS) bincur[i] = 0;
}

// Phase 1: LDS-binned edge scatter into per-bin FIFOs.
__global__ __launch_bounds__(256) void k_bin(const int* __restrict__ ei,
                                             int* __restrict__ bincur,
                                             unsigned* __restrict__ fifo) {
    __shared__ unsigned buf[NBINS][P1_BUF];   // 25 KB
    __shared__ int lcnt[NBINS];
    __shared__ int lbase[NBINS];
    const int tid = threadIdx.x;
    for (int j = tid; j < NBINS; j += 256) lcnt[j] = 0;
    __syncthreads();

    const int e0 = blockIdx.x * P1_CHUNK;
    #pragma unroll
    for (int i = 0; i < P1_CHUNK / 256; ++i) {
        int e = e0 + i * 256 + tid;
        if (e < EE) {
            int s = ei[e];
            int d = ei[EE + e];
            int bin = d >> 8;
            unsigned pk = ((unsigned)s << 8) | (unsigned)(d & 255);
            int p = atomicAdd(&lcnt[bin], 1);          // LDS atomic
            if (p < P1_BUF) {
                buf[bin][p] = pk;
            } else {                                   // rare overflow: direct append
                int gp = atomic_add_i32(&bincur[bin], 1);
                if (gp < FIFO_CAP) fifo[(size_t)bin * FIFO_CAP + gp] = pk;
            }
        }
    }
    __syncthreads();
    for (int j = tid; j < NBINS; j += 256) {
        int cnt = lcnt[j]; if (cnt > P1_BUF) cnt = P1_BUF;
        lbase[j] = (cnt > 0) ? atomic_add_i32(&bincur[j], cnt) : 0;
        lcnt[j] = cnt;
    }
    __syncthreads();
    for (int j = tid; j < NBINS; j += 256) {
        int cnt = lcnt[j];
        int base = lbase[j];
        for (int k = 0; k < cnt; ++k) {
            int gp = base + k;
            if (gp < FIFO_CAP) fifo[(size_t)j * FIFO_CAP + gp] = buf[j][k];
        }
    }
}

// Phase 2: one WG per bin. Replay FIFO with LDS atomics into LDS CSR tile,
// pad each bucket to a multiple of 8 with the zero-row index NN, flush int4.
__global__ __launch_bounds__(256) void k_csr(const int* __restrict__ bincur,
                                             const unsigned* __restrict__ fifo,
                                             int* __restrict__ csr,
                                             int* __restrict__ deg,
                                             float* __restrict__ dinv) {
    __shared__ int cur[BIN_NODES];                 // 1 KB
    __shared__ int stage[BIN_NODES * BUCKET];      // 48 KB
    const int tid = threadIdx.x;
    const int bin = blockIdx.x;
    const int v0 = bin * BIN_NODES;
    const int nnode = (NN - v0 < BIN_NODES) ? (NN - v0) : BIN_NODES;
    if (tid < BIN_NODES) cur[tid] = 0;
    __syncthreads();

    int cnt = bincur[bin]; if (cnt > FIFO_CAP) cnt = FIFO_CAP;
    for (int k = tid; k < cnt; k += 256) {
        unsigned u = fifo[(size_t)bin * FIFO_CAP + k];
        int dl = u & 255;
        int s = (int)(u >> 8);
        int p = atomicAdd(&cur[dl], 1);            // LDS atomic
        if (p < BUCKET) stage[dl * BUCKET + p] = s;
    }
    __syncthreads();

    if (tid < nnode) {                             // pad to multiple of 8 with NN
        int d = cur[tid]; if (d > BUCKET) d = BUCKET;
        int dpad = (d + 7) & ~7; if (dpad > BUCKET) dpad = BUCKET;
        for (int k = d; k < dpad; ++k) stage[tid * BUCKET + k] = NN;
        cur[tid] = d;
    }
    __syncthreads();

    const int total4 = nnode * BUCKET / 4;
    int4* dst4 = (int4*)&csr[(size_t)v0 * BUCKET];
    for (int idx = tid; idx < total4; idx += 256)
        dst4[idx] = *(const int4*)&stage[idx * 4];
    if (tid < nnode) {
        int d = cur[tid];
        deg[v0 + tid] = d;
        dinv[v0 + tid] = rsqrtf((float)(d + 1));
    }
}

// h1s = fp16( dinv * (x @ W1) ); row NN = exact zeros. Block: 64 rows, 4 waves.
__global__ __launch_bounds__(256) void k_gemm1(const float* __restrict__ x,
                                               const _Float16* __restrict__ w1t,
                                               const float* __restrict__ dinv,
                                               _Float16* __restrict__ h1s) {
    __shared__ _Float16 As[64 * IN_F];
    __shared__ _Float16 Bs[64 * IN_F];
    const int tid = threadIdx.x;
    const size_t r0 = (size_t)blockIdx.x * 64;

    #pragma unroll
    for (int i = 0; i < 8; ++i) {
        int f = i * 256 + tid;
        int row = f >> 5;
        int k4 = (f & 31) * 4;
        size_t gr = r0 + row; if (gr >= NN) gr = NN - 1;
        float4 v = *(const float4*)&x[gr * IN_F + k4];
        _Float16 h[4] = {(_Float16)v.x, (_Float16)v.y, (_Float16)v.z, (_Float16)v.w};
        *(uint2*)((char*)As + SWZ(row * 256 + k4 * 2, row)) = *(uint2*)h;
    }
    #pragma unroll
    for (int i = 0; i < 4; ++i) {
        int c = i * 256 + tid;
        int col = c >> 4;
        int k8 = (c & 15) * 8;
        uint4 v = *(const uint4*)&w1t[col * IN_F + k8];
        *(uint4*)((char*)Bs + SWZ(col * 256 + k8 * 2, col)) = v;
    }
    __syncthreads();

    const int w = tid >> 6, l = tid & 63;
    const int lr = l & 15, lg = l >> 4;
    const int R0 = w * 16;
    f32x4 acc[4] = {};
    #pragma unroll
    for (int kk = 0; kk < 4; ++kk) {
        const int kbyte = (kk * 32 + lg * 8) * 2;
        const int arow = R0 + lr;
        half8 a = *(const half8*)((const char*)As + SWZ(arow * 256 + kbyte, arow));
        #pragma unroll
        for (int t = 0; t < 4; ++t) {
            const int bcol = t * 16 + lr;
            half8 b = *(const half8*)((const char*)Bs + SWZ(bcol * 256 + kbyte, bcol));
            acc[t] = __builtin_amdgcn_mfma_f32_16x16x32_f16(a, b, acc[t], 0, 0, 0);
        }
    }
    #pragma unroll
    for (int r = 0; r < 4; ++r) {
        size_t row = r0 + R0 + lg * 4 + r;
        if (row < NN) {
            float dv = dinv[row];
            #pragma unroll
            for (int t = 0; t < 4; ++t)
                h1s[row * HID_F + t * 16 + lr] = (_Float16)(dv * acc[t][r]);
        } else if (row == NN) {
            #pragma unroll
            for (int t = 0; t < 4; ++t)
                h1s[row * HID_F + t * 16 + lr] = (_Float16)0.f;   // zero row
        }
    }
}

// FUSED agg1 + gemm2: 64 nodes/block. 8-wide padded gather (no remainder).
__global__ __launch_bounds__(256) void k_agg1g2(const _Float16* __restrict__ h1s,
                                                const float* __restrict__ dinv,
                                                const int* __restrict__ degA,
                                                const int* __restrict__ csr,
                                                const float* __restrict__ b1,
                                                const _Float16* __restrict__ w2t,
                                                _Float16* __restrict__ tabA,
                                                _Float16* __restrict__ tabB) {
    __shared__ _Float16 As[64 * HID_F];  // 8 KB, swizzled rows of 128B
    __shared__ _Float16 Bs[48 * HID_F];  // 6 KB
    const int tid = threadIdx.x;
    const size_t r0 = (size_t)blockIdx.x * 64;

    for (int cB = tid; cB < 384; cB += 256) {
        int col = cB >> 3;
        int k8 = (cB & 7) * 8;
        uint4 vB = *(const uint4*)&w2t[col * HID_F + k8];
        *(uint4*)((char*)Bs + SWZ(col * 128 + k8 * 2, col)) = vB;
    }

    const int grp = tid >> 4;   // 0..15
    const int c = tid & 15;
    float4 bb = *(const float4*)&b1[c * 4];
    #pragma unroll
    for (int i = 0; i < 4; ++i) {
        const int row = grp + i * 16;
        const size_t v = r0 + row;
        if (v >= NN) continue;

        int dg = degA[v];
        if (dg > BUCKET) dg = BUCKET;
        const int iters = (dg + 7) >> 3;
        const int4* cp = (const int4*)&csr[(size_t)v * BUCKET];

        f32x4 accA = h4f4(*(const half4*)&h1s[(v << 6) + c * 4]);   // self
        f32x4 accB = {};
        for (int it = 0; it < iters; ++it) {
            int4 sa = cp[2 * it];
            int4 sb = cp[2 * it + 1];
            half4 a0 = *(const half4*)&h1s[((size_t)sa.x << 6) + c * 4];
            half4 a1 = *(const half4*)&h1s[((size_t)sa.y << 6) + c * 4];
            half4 a2 = *(const half4*)&h1s[((size_t)sa.z << 6) + c * 4];
            half4 a3 = *(const half4*)&h1s[((size_t)sa.w << 6) + c * 4];
            half4 a4 = *(const half4*)&h1s[((size_t)sb.x << 6) + c * 4];
            half4 a5 = *(const half4*)&h1s[((size_t)sb.y << 6) + c * 4];
            half4 a6 = *(const half4*)&h1s[((size_t)sb.z << 6) + c * 4];
            half4 a7 = *(const half4*)&h1s[((size_t)sb.w << 6) + c * 4];
            accA += h4f4(a0); accB += h4f4(a1); accA += h4f4(a2); accB += h4f4(a3);
            accA += h4f4(a4); accB += h4f4(a5); accA += h4f4(a6); accB += h4f4(a7);
        }
        accA += accB;

        const float dv = dinv[v];
        _Float16 o[4];
        o[0] = (_Float16)fmaxf(dv * accA[0] + bb.x, 0.f);
        o[1] = (_Float16)fmaxf(dv * accA[1] + bb.y, 0.f);
        o[2] = (_Float16)fmaxf(dv * accA[2] + bb.z, 0.f);
        o[3] = (_Float16)fmaxf(dv * accA[3] + bb.w, 0.f);
        *(uint2*)((char*)As + SWZ(row * 128 + c * 8, row)) = *(uint2*)o;
    }
    __syncthreads();

    const int w = tid >> 6, l = tid & 63;
    const int lr = l & 15, lg = l >> 4;
    const int R0 = w * 16;
    f32x4 acc[3] = {};
    #pragma unroll
    for (int kk = 0; kk < 2; ++kk) {
        const int kbyte = (kk * 32 + lg * 8) * 2;
        const int arow = R0 + lr;
        half8 a = *(const half8*)((const char*)As + SWZ(arow * 128 + kbyte, arow));
        #pragma unroll
        for (int t = 0; t < 3; ++t) {
            const int bcol = t * 16 + lr;
            half8 b = *(const half8*)((const char*)Bs + SWZ(bcol * 128 + kbyte, bcol));
            acc[t] = __builtin_amdgcn_mfma_f32_16x16x32_f16(a, b, acc[t], 0, 0, 0);
        }
    }
    #pragma unroll
    for (int r = 0; r < 4; ++r) {
        size_t row = r0 + R0 + lg * 4 + r;
        if (row < NN) {
            float dv = dinv[row];
            #pragma unroll
            for (int t = 0; t < 3; ++t) {
                int col = t * 16 + lr;
                float val = dv * acc[t][r];
                if (col < 32) tabA[row * 32 + col] = (_Float16)val;
                else if (col < OUT_F) tabB[row * 8 + (col - 32)] = (_Float16)val;
            }
        } else if (row == NN) {                     // zero row for pad gathers
            #pragma unroll
            for (int t = 0; t < 3; ++t) {
                int col = t * 16 + lr;
                if (col < 32) tabA[row * 32 + col] = (_Float16)0.f;
                else if (col < OUT_F) tabB[row * 8 + (col - 32)] = (_Float16)0.f;
            }
        }
    }
}

// agg2: 16-lane group per node; 8-wide padded gather; lanes 0-7 tabA, 8-9 tabB.
__global__ __launch_bounds__(256) void k_agg2(const _Float16* __restrict__ tabA,
                                              const _Float16* __restrict__ tabB,
                                              const float* __restrict__ dinv,
                                              const int* __restrict__ degA,
                                              const int* __restrict__ csr,
                                              const float* __restrict__ b2,
                                              float* __restrict__ out) {
    const int tid = threadIdx.x;
    const int v = blockIdx.x * 16 + (tid >> 4);
    if (v >= NN) return;
    const int c = tid & 15;
    const bool useA = (c < 8);
    const size_t aoff = useA ? (size_t)c * 4 : 0;
    const size_t boff = (c >= 8 && c < 10) ? (size_t)(c - 8) * 4 : 0;

    int dg = degA[v];
    if (dg > BUCKET) dg = BUCKET;
    const int iters = (dg + 7) >> 3;
    const int4* cp = (const int4*)&csr[(size_t)v * BUCKET];

    f32x4 accA, accB = {};
    {
        const _Float16* p = useA ? tabA + ((size_t)v << 5) + aoff : tabB + ((size_t)v << 3) + boff;
        accA = h4f4(*(const half4*)p);   // self
    }
    for (int it = 0; it < iters; ++it) {
        int4 sa = cp[2 * it];
        int4 sb = cp[2 * it + 1];
        const _Float16* p0 = useA ? tabA + ((size_t)sa.x << 5) + aoff : tabB + ((size_t)sa.x << 3) + boff;
        const _Float16* p1 = useA ? tabA + ((size_t)sa.y << 5) + aoff : tabB + ((size_t)sa.y << 3) + boff;
        const _Float16* p2 = useA ? tabA + ((size_t)sa.z << 5) + aoff : tabB + ((size_t)sa.z << 3) + boff;
        const _Float16* p3 = useA ? tabA + ((size_t)sa.w << 5) + aoff : tabB + ((size_t)sa.w << 3) + boff;
        const _Float16* p4 = useA ? tabA + ((size_t)sb.x << 5) + aoff : tabB + ((size_t)sb.x << 3) + boff;
        const _Float16* p5 = useA ? tabA + ((size_t)sb.y << 5) + aoff : tabB + ((size_t)sb.y << 3) + boff;
        const _Float16* p6 = useA ? tabA + ((size_t)sb.z << 5) + aoff : tabB + ((size_t)sb.z << 3) + boff;
        const _Float16* p7 = useA ? tabA + ((size_t)sb.w << 5) + aoff : tabB + ((size_t)sb.w << 3) + boff;
        half4 a0 = *(const half4*)p0;
        half4 a1 = *(const half4*)p1;
        half4 a2 = *(const half4*)p2;
        half4 a3 = *(const half4*)p3;
        half4 a4 = *(const half4*)p4;
        half4 a5 = *(const half4*)p5;
        half4 a6 = *(const half4*)p6;
        half4 a7 = *(const half4*)p7;
        accA += h4f4(a0); accB += h4f4(a1); accA += h4f4(a2); accB += h4f4(a3);
        accA += h4f4(a4); accB += h4f4(a5); accA += h4f4(a6); accB += h4f4(a7);
    }
    accA += accB;

    if (c < 10) {
        const float dv = dinv[v];
        float4 bb = *(const float4*)&b2[c * 4];
        float4 o = {dv * accA[0] + bb.x, dv * accA[1] + bb.y,
                    dv * accA[2] + bb.z, dv * accA[3] + bb.w};
        *(float4*)&out[(size_t)v * OUT_F + c * 4] = o;
    }
}

extern "C" void kernel_launch(void* const* d_in, const int* in_sizes, int n_in,
                              void* d_out, int out_size, void* d_ws, size_t ws_size,
                              hipStream_t stream) {
    const float* x  = (const float*)d_in[0];
    const int*   ei = (const int*)d_in[1];
    const float* W1 = (const float*)d_in[2];
    const float* b1 = (const float*)d_in[3];
    const float* W2 = (const float*)d_in[4];
    const float* b2 = (const float*)d_in[5];
    float* out = (float*)d_out;

    char* p = (char*)d_ws;
    float*     dinv   = (float*)p;     p += (size_t)NN * 4;
    int*       deg    = (int*)p;       p += (size_t)NN * 4;
    int*       bincur = (int*)p;       p += 512 * 4;
    unsigned*  fifo   = (unsigned*)p;  p += (size_t)NBINS * FIFO_CAP * 4;
    _Float16*  w1t    = (_Float16*)p;  p += (size_t)IN_F * HID_F * 2;
    _Float16*  w2t    = (_Float16*)p;  p += (size_t)48 * HID_F * 2;
    int*       csr    = (int*)p;       p += (size_t)NN * BUCKET * 4;
    _Float16*  h1s    = (_Float16*)p;  p += (size_t)(NN + 1) * HID_F * 2;  // +zero row
    _Float16*  tabA   = (_Float16*)p;  p += (size_t)(NN + 1) * 32 * 2;     // +zero row
    _Float16*  tabB   = (_Float16*)p;  p += ((size_t)(NN + 1) * 8 + 32) * 2;

    const int gemm_blocks = (NN + 63) / 64;     // covers rows 0..100031 ⊇ row NN
    const int agg2_blocks = (NN + 15) / 16;
    const int bin_blocks = (EE + P1_CHUNK - 1) / P1_CHUNK;

    k_prep  <<<32, 256, 0, stream>>>(W1, W2, w1t, w2t, bincur);
    k_bin   <<<bin_blocks, 256, 0, stream>>>(ei, bincur, fifo);
    k_csr   <<<NBINS, 256, 0, stream>>>(bincur, fifo, csr, deg, dinv);
    k_gemm1 <<<gemm_blocks, 256, 0, stream>>>(x, w1t, dinv, h1s);
    k_agg1g2<<<gemm_blocks, 256, 0, stream>>>(h1s, dinv, deg, csr, b1, w2t, tabA, tabB);
    k_agg2  <<<agg2_blocks, 256, 0, stream>>>(tabA, tabB, dinv, deg, csr, b2, out);
}